// Round 8
// baseline (357.463 us; speedup 1.0000x reference)
//
#include <hip/hip_runtime.h>
#include <hip/hip_bf16.h>
#include <math.h>

// Causal attention fwd: B=1,H=16,S=4096,D=64 fp32 in/out.
// 32x32x16-MFMA flash kernel, swapped QK^T (S^T = K*Q), in-register softmax,
// defer-max (THR=8, exp2 domain). Round 7:
//  - KB=64, double-buffered LDS 32KB -> 4 blocks/CU, grid 1024 (TLP 2x)
//  - ONE barrier per KV-iter (dbuf makes the 2nd provably redundant)
//  - balanced midpoint split-K, ws-adaptive (s=8 / s=16 / monolithic)
// Block: 256 thr = 4 waves x 32 q-rows (QB=128).

typedef __bf16 bf16;
typedef __bf16 bf16x8 __attribute__((ext_vector_type(8)));
typedef float f32x16 __attribute__((ext_vector_type(16)));

#define NH 16
#define SEQ 4096
#define DH 64
#define QB 128
#define WQ 32
#define KB 64
#define LOG2E 1.44269504088896340736f

// ws layout (runtime by s): [0]=counter; O @256 (nslot*128*64 bf16);
// M @256+nslot*16384; L after (nslot*128 f32 each). nslot=(32-s)*32.
#define NEED8  13369600ull
#define NEED16 8913152ull

static __device__ __forceinline__ void mfma32(f32x16& c, bf16x8 a, bf16x8 b) {
  asm("v_mfma_f32_32x32x16_bf16 %0, %1, %2, %0" : "+v"(c) : "v"(a), "v"(b));
}
static __device__ __forceinline__ float exp2a(float x) {
  float r; asm("v_exp_f32 %0, %1" : "=v"(r) : "v"(x)); return r;
}
static __device__ __forceinline__ unsigned pk(float lo, float hi) {
  unsigned r; asm("v_cvt_pk_bf16_f32 %0, %1, %2" : "=v"(r) : "v"(lo), "v"(hi)); return r;
}
static __device__ __forceinline__ void swap32(unsigned& a, unsigned& b) {
  asm("v_permlane32_swap_b32 %0, %1" : "+v"(a), "+v"(b));
}

union AFrag { unsigned u[4]; bf16x8 v; };

static __device__ __forceinline__ bf16x8 cvt8(float4 a, float4 b) {
  bf16x8 f;
  f[0]=(bf16)a.x; f[1]=(bf16)a.y; f[2]=(bf16)a.z; f[3]=(bf16)a.w;
  f[4]=(bf16)b.x; f[5]=(bf16)b.y; f[6]=(bf16)b.z; f[7]=(bf16)b.w;
  return f;
}

__global__ void zero_ctr(unsigned* c) { if (threadIdx.x == 0) *c = 0; }

__global__ __launch_bounds__(256, 4)
void fa_fwd(const float* __restrict__ Q, const float* __restrict__ K,
            const float* __restrict__ V, float* __restrict__ O,
            void* __restrict__ ws, const int nitems, const int s) {
  __shared__ bf16 Ksh[2][KB * DH];   // [buf][k][d]  8KB each, row 128B
  __shared__ bf16 Vts[2][DH * KB];   // [buf][d][k]  8KB each, row 128B
  __shared__ int sh_item;

  unsigned* ctr = (unsigned*)ws;
  const int ns    = 32 - s;
  const int nslot = 32 * ns;
  bf16*  wsO = (bf16*)((char*)ws + 256);
  float* wsM = (float*)((char*)ws + 256 + (size_t)nslot * 16384);
  float* wsL = wsM + (size_t)nslot * 128;

  const int tid = threadIdx.x;
  const int w   = tid >> 6;
  const int l   = tid & 63;
  const int lc  = l & 31;
  const int hi  = l >> 5;

  // staging assignments (KB=64)
  const int kr = tid >> 2, kc = (tid & 3) * 16;  // K: row, 16-col group
  const int dg = tid & 7,  kp = tid >> 3;        // V: d-group(8), k-pair [0,32)

  for (;;) {
    __syncthreads();   // prev item's LDS reads done; sh_item reusable
    if (tid == 0) sh_item = (int)atomicAdd(ctr, 1u);
    __syncthreads();
    const int c = sh_item;
    if (c >= nitems) break;   // uniform

    // ---- decode: (head, qb, tile range [t0,t1) in 64-key units, slot) ----
    int head, qb, t0, t1, slot = -1;
    if (c < ns * 16) {                 // chunk 0, heavy-first
      head = c & 15; const int j = 31 - (c >> 4);
      qb = j * QB; t0 = 0; t1 = j + 1;
      slot = ((j - s) * 16 + head) * 2;
    } else if (c < 2 * ns * 16) {      // chunk 1, heavy-first
      const int i = c - ns * 16;
      head = i & 15; const int j = 31 - (i >> 4);
      qb = j * QB; t0 = j + 1; t1 = 2 * j + 2;
      slot = ((j - s) * 16 + head) * 2 + 1;
    } else {                           // unsplit, heavy-first
      const int i = c - 2 * ns * 16;
      head = i & 15; const int j = (s - 1) - (i >> 4);
      qb = j * QB; t0 = 0; t1 = 2 * j + 2;
    }

    const int qw = qb + w * WQ;
    const int qv = qw + lc;
    const float* Qh = Q + (size_t)head * SEQ * DH;
    const float* Kh = K + (size_t)head * SEQ * DH;
    const float* Vh = V + (size_t)head * SEQ * DH;

    // ---- Q as B-fragments (scale folds 1/8 and log2e) ----
    bf16x8 qf[4];
    {
      const float* qp = Qh + (size_t)qv * DH + hi * 8;
      const float sc = 0.125f * LOG2E;
#pragma unroll
      for (int ch = 0; ch < 4; ++ch) {
        float4 x = *(const float4*)(qp + ch * 16);
        float4 y = *(const float4*)(qp + ch * 16 + 4);
        bf16x8 f;
        f[0]=(bf16)(x.x*sc); f[1]=(bf16)(x.y*sc); f[2]=(bf16)(x.z*sc); f[3]=(bf16)(x.w*sc);
        f[4]=(bf16)(y.x*sc); f[5]=(bf16)(y.y*sc); f[6]=(bf16)(y.z*sc); f[7]=(bf16)(y.w*sc);
        qf[ch] = f;
      }
    }

    f32x16 o0 = {}, o1 = {};
    float m = -INFINITY, ls = 0.f;

    float4 kreg[4], vreg[4];
    // ---- load first tile into regs ----
    {
      const int kb0 = t0 * KB;
      const float* p = Kh + (size_t)(kb0 + kr) * DH + kc;
#pragma unroll
      for (int i = 0; i < 4; ++i) kreg[i] = ((const float4*)p)[i];
      const float* pv = Vh + (size_t)(kb0 + 2 * kp) * DH + dg * 8;
      vreg[0] = ((const float4*)pv)[0];
      vreg[1] = ((const float4*)pv)[1];
      vreg[2] = ((const float4*)(pv + DH))[0];
      vreg[3] = ((const float4*)(pv + DH))[1];
    }

    for (int t = t0; t < t1; ++t) {
      const int kb = t * KB;
      const int b  = (t - t0) & 1;

      // ---- write regs -> LDS[b] (swizzled) ----
      {
        const int Sk = (((kr & 7) ^ ((kr >> 3) & 7)) << 4);
#pragma unroll
        for (int q = 0; q < 2; ++q)
          *(bf16x8*)((char*)Ksh[b] + kr * 128 + ((kc * 2 + q * 16) ^ Sk)) =
              cvt8(kreg[2*q], kreg[2*q+1]);
        const int xbase = (kp * 4) ^ (dg << 4);
#pragma unroll
        for (int i = 0; i < 8; ++i) {
          const float lo = vreg[(i >> 2)    ][i & 3];
          const float hv = vreg[(i >> 2) + 2][i & 3];
          *(unsigned*)((char*)Vts[b] + (dg * 8 + i) * 128 + (xbase ^ (i << 4))) =
              pk(lo, hv);
        }
      }
      __syncthreads();   // single barrier per iter (dbuf covers the rest)

      // ---- issue next tile's loads early (hidden under compute) ----
      if (t + 1 < t1) {
        const int kn = kb + KB;
        const float* p = Kh + (size_t)(kn + kr) * DH + kc;
#pragma unroll
        for (int i = 0; i < 4; ++i) kreg[i] = ((const float4*)p)[i];
        const float* pv = Vh + (size_t)(kn + 2 * kp) * DH + dg * 8;
        vreg[0] = ((const float4*)pv)[0];
        vreg[1] = ((const float4*)pv)[1];
        vreg[2] = ((const float4*)(pv + DH))[0];
        vreg[3] = ((const float4*)(pv + DH))[1];
      }

      if (kb > qw + 31) continue;   // wave fully masked (barrier already done)

      // ---- S^T = K*Q on LDS[b] ----
      f32x16 st0 = {}, st1 = {};
#pragma unroll
      for (int kt = 0; kt < 2; ++kt) {
        const int row = kt * 32 + lc;
        const int Sr  = (((lc & 7) ^ ((kt * 4 + (lc >> 3)) & 7)) << 4);
        f32x16& st = kt ? st1 : st0;
#pragma unroll
        for (int ch = 0; ch < 4; ++ch) {
          const bf16x8 kf = *(const bf16x8*)((const char*)Ksh[b] +
              row * 128 + ((ch * 32 + hi * 16) ^ Sr));
          mfma32(st, kf, qf[ch]);
        }
      }

      if (kb + 63 > qw) {   // causal mask near diagonal
#pragma unroll
        for (int r = 0; r < 16; ++r) {
          const int kg = kb + ((r & 3) + 8 * (r >> 2) + 4 * hi);
          if (kg > qv)      st0[r] = -INFINITY;
          if (kg + 32 > qv) st1[r] = -INFINITY;
        }
      }

      // row max
      float acc[8];
#pragma unroll
      for (int i = 0; i < 8; ++i)
        acc[i] = fmaxf(fmaxf(st0[i], st0[i + 8]), fmaxf(st1[i], st1[i + 8]));
      acc[0]=fmaxf(acc[0],acc[4]); acc[1]=fmaxf(acc[1],acc[5]);
      acc[2]=fmaxf(acc[2],acc[6]); acc[3]=fmaxf(acc[3],acc[7]);
      acc[0]=fmaxf(acc[0],acc[2]); acc[1]=fmaxf(acc[1],acc[3]);
      float mx = fmaxf(acc[0], acc[1]);
      mx = fmaxf(mx, __shfl_xor(mx, 32));

      // defer-max rescale
      if (__any(mx > m + 8.0f)) {
        const float mn = fmaxf(m, mx);
        const float al = exp2a(m - mn);
        m = mn;
        ls *= al;
#pragma unroll
        for (int r = 0; r < 16; ++r) {
          const float aq = __shfl(al, (r & 3) + 8 * (r >> 2) + 4 * hi);
          o0[r] *= aq; o1[r] *= aq;
        }
      }

      // P = exp2(S-m), pack -> A-frag, consume in PV
      float rs = 0.f;
      const int S0 = (((lc & 7) ^ ((lc >> 3) & 7)) << 4);
      const int S1 = (((lc & 7) ^ (((lc >> 3) + 4) & 7)) << 4);
#pragma unroll
      for (int ks = 0; ks < 4; ++ks) {
        const f32x16& st = (ks < 2) ? st0 : st1;
        float p[8];
#pragma unroll
        for (int j = 0; j < 8; ++j) p[j] = exp2a(st[(ks & 1) * 8 + j] - m);
        rs += ((p[0]+p[1])+(p[2]+p[3])) + ((p[4]+p[5])+(p[6]+p[7]));
        unsigned u0 = pk(p[0],p[1]), u1 = pk(p[2],p[3]);
        unsigned u2 = pk(p[4],p[5]), u3 = pk(p[6],p[7]);
        swap32(u0, u2); swap32(u1, u3);
        AFrag af; af.u[0]=u0; af.u[1]=u1; af.u[2]=u2; af.u[3]=u3;
        const int koff = ks * 32 + hi * 16;
        bf16x8 v0 = *(const bf16x8*)((const char*)Vts[b] + lc * 128 + (koff ^ S0));
        bf16x8 v1 = *(const bf16x8*)((const char*)Vts[b] + (lc + 32) * 128 + (koff ^ S1));
        mfma32(o0, af.v, v0);
        mfma32(o1, af.v, v1);
      }
      rs += __shfl_xor(rs, 32);
      ls += rs;
    }

    // ---- epilogue ----
    if (slot < 0) {
      const float inv = 1.0f / ls;
      float* Ob = O + (size_t)(head * SEQ + qw) * DH;
#pragma unroll
      for (int r = 0; r < 16; ++r) {
        const int row = (r & 3) + 8 * (r >> 2) + 4 * hi;
        const float iq = __shfl(inv, row);
        Ob[(size_t)row * DH + lc]      = o0[r] * iq;
        Ob[(size_t)row * DH + 32 + lc] = o1[r] * iq;
      }
    } else {
      bf16* po = wsO + (size_t)slot * (128 * 64);
#pragma unroll
      for (int r = 0; r < 16; ++r) {
        const int row = w * WQ + (r & 3) + 8 * (r >> 2) + 4 * hi;
        po[row * 64 + lc]      = (bf16)o0[r];
        po[row * 64 + 32 + lc] = (bf16)o1[r];
      }
      if (hi == 0) {
        wsM[slot * 128 + w * WQ + lc] = m;
        wsL[slot * 128 + w * WQ + lc] = ls;
      }
    }
  }
}

// merge the two partials per split q-block (exact online-softmax merge)
__global__ __launch_bounds__(256)
void fa_combine(float* __restrict__ O, const void* __restrict__ ws, const int s) {
  const int ns    = 32 - s;
  const int nslot = 32 * ns;
  const bf16*  wsO = (const bf16*)((const char*)ws + 256);
  const float* wsM = (const float*)((const char*)ws + 256 + (size_t)nslot * 16384);
  const float* wsL = wsM + (size_t)nslot * 128;

  const int li    = blockIdx.x * 256 + threadIdx.x;   // [0, 1024)
  const int dpart = li & 7;
  const int r     = li >> 3;                          // [0, 128)
  const int jj    = blockIdx.y;                       // [0, ns)
  const int h     = blockIdx.z;                       // [0, 16)
  const int s0    = (jj * 16 + h) * 2;

  const float m0 = wsM[s0 * 128 + r], m1 = wsM[(s0 + 1) * 128 + r];
  const float l0 = wsL[s0 * 128 + r], l1 = wsL[(s0 + 1) * 128 + r];
  const float M  = fmaxf(m0, m1);
  const float w0 = exp2f(m0 - M), w1 = exp2f(m1 - M);
  const float inv = 1.0f / (l0 * w0 + l1 * w1);

  const bf16x8 a = *(const bf16x8*)(wsO + (size_t)s0 * 8192 + r * 64 + dpart * 8);
  const bf16x8 b = *(const bf16x8*)(wsO + (size_t)(s0 + 1) * 8192 + r * 64 + dpart * 8);

  float* out = O + ((size_t)h * SEQ + (s + jj) * 128 + r) * DH + dpart * 8;
#pragma unroll
  for (int j = 0; j < 8; ++j)
    out[j] = ((float)a[j] * w0 + (float)b[j] * w1) * inv;
}

extern "C" void kernel_launch(void* const* d_in, const int* in_sizes, int n_in,
                              void* d_out, int out_size, void* d_ws, size_t ws_size,
                              hipStream_t stream) {
  const float* q = (const float*)d_in[0];
  const float* k = (const float*)d_in[1];
  const float* v = (const float*)d_in[2];
  float* out = (float*)d_out;

  int s;
  if      (ws_size >= NEED8)  s = 8;
  else if (ws_size >= NEED16) s = 16;
  else                        s = 32;   // monolithic fallback
  const int ns = 32 - s;
  const int nitems = 2 * ns * 16 + s * 16;

  zero_ctr<<<1, 64, 0, stream>>>((unsigned*)d_ws);
  fa_fwd<<<1024, 256, 0, stream>>>(q, k, v, out, d_ws, nitems, s);
  if (ns > 0) fa_combine<<<dim3(4, ns, 16), 256, 0, stream>>>(out, d_ws, s);
}

// Round 9
// 221.385 us; speedup vs baseline: 1.6147x; 1.6147x over previous
//
#include <hip/hip_runtime.h>
#include <hip/hip_bf16.h>
#include <math.h>

// Causal attention fwd: B=1,H=16,S=4096,D=64 fp32 in/out.
// 32x32x16-MFMA flash kernel, swapped QK^T (S^T = K*Q), in-register softmax,
// defer-max (THR=8, exp2 domain), KB=64 double-buffered LDS (32KB), one
// barrier/iter, work-stealing. Round 9:
//  - launch_bounds(256,3): cap 170 regs -> NO SPILL (round 8: cap 128 ->
//    64 VGPR + 260MB scratch traffic = the whole regression)
//  - ws-adaptive split-K: chunk length Lt in {16,22,32} tiles picked from
//    actual ws_size (20.1/14.5/8.9 MB); monolithic fallback. Heavy-first.

typedef __bf16 bf16;
typedef __bf16 bf16x8 __attribute__((ext_vector_type(8)));
typedef float f32x16 __attribute__((ext_vector_type(16)));

#define NH 16
#define SEQ 4096
#define DH 64
#define QB 128
#define WQ 32
#define KB 64
#define NJ 32
#define LOG2E 1.44269504088896340736f

static __device__ __forceinline__ void mfma32(f32x16& c, bf16x8 a, bf16x8 b) {
  asm("v_mfma_f32_32x32x16_bf16 %0, %1, %2, %0" : "+v"(c) : "v"(a), "v"(b));
}
static __device__ __forceinline__ float exp2a(float x) {
  float r; asm("v_exp_f32 %0, %1" : "=v"(r) : "v"(x)); return r;
}
static __device__ __forceinline__ unsigned pk(float lo, float hi) {
  unsigned r; asm("v_cvt_pk_bf16_f32 %0, %1, %2" : "=v"(r) : "v"(lo), "v"(hi)); return r;
}
static __device__ __forceinline__ void swap32(unsigned& a, unsigned& b) {
  asm("v_permlane32_swap_b32 %0, %1" : "+v"(a), "+v"(b));
}

union AFrag { unsigned u[4]; bf16x8 v; };

static __device__ __forceinline__ bf16x8 cvt8(float4 a, float4 b) {
  bf16x8 f;
  f[0]=(bf16)a.x; f[1]=(bf16)a.y; f[2]=(bf16)a.z; f[3]=(bf16)a.w;
  f[4]=(bf16)b.x; f[5]=(bf16)b.y; f[6]=(bf16)b.z; f[7]=(bf16)b.w;
  return f;
}

__global__ void zero_ctr(unsigned* c) { if (threadIdx.x == 0) *c = 0; }

// ws layout: [0]=counter; O @256 (nslot*16384 B bf16); M @256+nslot*16384
// (nslot*512 B f32); L after (nslot*512 B f32). slot = (sbase+ci)*16+head.

__global__ __launch_bounds__(256, 3)
void fa_fwd(const float* __restrict__ Q, const float* __restrict__ K,
            const float* __restrict__ V, float* __restrict__ O,
            void* __restrict__ ws, const int nitems, const int Lt,
            const int nslot) {
  __shared__ bf16 Ksh[2][KB * DH];   // [buf][k][d]  8KB each, row 128B
  __shared__ bf16 Vts[2][DH * KB];   // [buf][d][k]  8KB each, row 128B
  __shared__ int sh_item;

  unsigned* ctr = (unsigned*)ws;
  bf16*  wsO = (bf16*)((char*)ws + 256);
  float* wsM = (float*)((char*)ws + 256 + (size_t)nslot * 16384);
  float* wsL = wsM + (size_t)nslot * 128;

  const int tid = threadIdx.x;
  const int w   = tid >> 6;
  const int l   = tid & 63;
  const int lc  = l & 31;
  const int hi  = l >> 5;

  // staging assignments (KB=64)
  const int kr = tid >> 2, kc = (tid & 3) * 16;  // K: row, 16-col group
  const int dg = tid & 7,  kp = tid >> 3;        // V: d-group(8), k-pair [0,32)

  for (;;) {
    __syncthreads();   // prev item's LDS reads done; sh_item reusable
    if (tid == 0) sh_item = (int)atomicAdd(ctr, 1u);
    __syncthreads();
    const int c = sh_item;
    if (c >= nitems) break;   // uniform

    // ---- decode: heavy-first (j descending); (j, chunk ci, head) ----
    int j = 0, ci = 0, head = 0, sbase = 0, nc = 1;
    {
      int cc = c;
      for (int jj = NJ - 1; jj >= 0; --jj) {
        const int ncj = (2 * jj + 2 + Lt - 1) / Lt;
        const int cnt = ncj * NH;
        if (cc < cnt) { j = jj; nc = ncj; ci = cc >> 4; head = cc & 15; break; }
        cc -= cnt;
        if (ncj > 1) sbase += ncj;
      }
    }
    const int qb = j * QB;
    const int t0 = ci * Lt;
    const int t1 = min((ci + 1) * Lt, 2 * j + 2);
    const int slot = (nc > 1) ? (sbase + ci) * NH + head : -1;

    const int qw = qb + w * WQ;
    const int qv = qw + lc;
    const float* Qh = Q + (size_t)head * SEQ * DH;
    const float* Kh = K + (size_t)head * SEQ * DH;
    const float* Vh = V + (size_t)head * SEQ * DH;

    // ---- Q as B-fragments (scale folds 1/8 and log2e) ----
    bf16x8 qf[4];
    {
      const float* qp = Qh + (size_t)qv * DH + hi * 8;
      const float sc = 0.125f * LOG2E;
#pragma unroll
      for (int ch = 0; ch < 4; ++ch) {
        float4 x = *(const float4*)(qp + ch * 16);
        float4 y = *(const float4*)(qp + ch * 16 + 4);
        bf16x8 f;
        f[0]=(bf16)(x.x*sc); f[1]=(bf16)(x.y*sc); f[2]=(bf16)(x.z*sc); f[3]=(bf16)(x.w*sc);
        f[4]=(bf16)(y.x*sc); f[5]=(bf16)(y.y*sc); f[6]=(bf16)(y.z*sc); f[7]=(bf16)(y.w*sc);
        qf[ch] = f;
      }
    }

    f32x16 o0 = {}, o1 = {};
    float m = -INFINITY, ls = 0.f;

    float4 kreg[4], vreg[4];
    // ---- load first tile into regs ----
    {
      const int kb0 = t0 * KB;
      const float* p = Kh + (size_t)(kb0 + kr) * DH + kc;
#pragma unroll
      for (int i = 0; i < 4; ++i) kreg[i] = ((const float4*)p)[i];
      const float* pv = Vh + (size_t)(kb0 + 2 * kp) * DH + dg * 8;
      vreg[0] = ((const float4*)pv)[0];
      vreg[1] = ((const float4*)pv)[1];
      vreg[2] = ((const float4*)(pv + DH))[0];
      vreg[3] = ((const float4*)(pv + DH))[1];
    }

    for (int t = t0; t < t1; ++t) {
      const int kb = t * KB;
      const int b  = (t - t0) & 1;

      // ---- write regs -> LDS[b] (swizzled) ----
      {
        const int Sk = (((kr & 7) ^ ((kr >> 3) & 7)) << 4);
#pragma unroll
        for (int q = 0; q < 2; ++q)
          *(bf16x8*)((char*)Ksh[b] + kr * 128 + ((kc * 2 + q * 16) ^ Sk)) =
              cvt8(kreg[2*q], kreg[2*q+1]);
        const int xbase = (kp * 4) ^ (dg << 4);
#pragma unroll
        for (int i = 0; i < 8; ++i) {
          const float lo = vreg[(i >> 2)    ][i & 3];
          const float hv = vreg[(i >> 2) + 2][i & 3];
          *(unsigned*)((char*)Vts[b] + (dg * 8 + i) * 128 + (xbase ^ (i << 4))) =
              pk(lo, hv);
        }
      }
      __syncthreads();   // single barrier per iter (dbuf covers the rest)

      // ---- issue next tile's loads early (hidden under compute) ----
      if (t + 1 < t1) {
        const int kn = kb + KB;
        const float* p = Kh + (size_t)(kn + kr) * DH + kc;
#pragma unroll
        for (int i = 0; i < 4; ++i) kreg[i] = ((const float4*)p)[i];
        const float* pv = Vh + (size_t)(kn + 2 * kp) * DH + dg * 8;
        vreg[0] = ((const float4*)pv)[0];
        vreg[1] = ((const float4*)pv)[1];
        vreg[2] = ((const float4*)(pv + DH))[0];
        vreg[3] = ((const float4*)(pv + DH))[1];
      }

      if (kb > qw + 31) continue;   // wave fully masked (barrier already done)

      // ---- S^T = K*Q on LDS[b] ----
      f32x16 st0 = {}, st1 = {};
#pragma unroll
      for (int kt = 0; kt < 2; ++kt) {
        const int row = kt * 32 + lc;
        const int Sr  = (((lc & 7) ^ ((kt * 4 + (lc >> 3)) & 7)) << 4);
        f32x16& st = kt ? st1 : st0;
#pragma unroll
        for (int ch = 0; ch < 4; ++ch) {
          const bf16x8 kf = *(const bf16x8*)((const char*)Ksh[b] +
              row * 128 + ((ch * 32 + hi * 16) ^ Sr));
          mfma32(st, kf, qf[ch]);
        }
      }

      if (kb + 63 > qw) {   // causal mask near diagonal
#pragma unroll
        for (int r = 0; r < 16; ++r) {
          const int kg = kb + ((r & 3) + 8 * (r >> 2) + 4 * hi);
          if (kg > qv)      st0[r] = -INFINITY;
          if (kg + 32 > qv) st1[r] = -INFINITY;
        }
      }

      // row max
      float acc[8];
#pragma unroll
      for (int i = 0; i < 8; ++i)
        acc[i] = fmaxf(fmaxf(st0[i], st0[i + 8]), fmaxf(st1[i], st1[i + 8]));
      acc[0]=fmaxf(acc[0],acc[4]); acc[1]=fmaxf(acc[1],acc[5]);
      acc[2]=fmaxf(acc[2],acc[6]); acc[3]=fmaxf(acc[3],acc[7]);
      acc[0]=fmaxf(acc[0],acc[2]); acc[1]=fmaxf(acc[1],acc[3]);
      float mx = fmaxf(acc[0], acc[1]);
      mx = fmaxf(mx, __shfl_xor(mx, 32));

      // defer-max rescale
      if (__any(mx > m + 8.0f)) {
        const float mn = fmaxf(m, mx);
        const float al = exp2a(m - mn);
        m = mn;
        ls *= al;
#pragma unroll
        for (int r = 0; r < 16; ++r) {
          const float aq = __shfl(al, (r & 3) + 8 * (r >> 2) + 4 * hi);
          o0[r] *= aq; o1[r] *= aq;
        }
      }

      // P = exp2(S-m), pack -> A-frag, consume in PV
      float rs = 0.f;
      const int S0 = (((lc & 7) ^ ((lc >> 3) & 7)) << 4);
      const int S1 = (((lc & 7) ^ (((lc >> 3) + 4) & 7)) << 4);
#pragma unroll
      for (int ks = 0; ks < 4; ++ks) {
        const f32x16& st = (ks < 2) ? st0 : st1;
        float p[8];
#pragma unroll
        for (int jj = 0; jj < 8; ++jj) p[jj] = exp2a(st[(ks & 1) * 8 + jj] - m);
        rs += ((p[0]+p[1])+(p[2]+p[3])) + ((p[4]+p[5])+(p[6]+p[7]));
        unsigned u0 = pk(p[0],p[1]), u1 = pk(p[2],p[3]);
        unsigned u2 = pk(p[4],p[5]), u3 = pk(p[6],p[7]);
        swap32(u0, u2); swap32(u1, u3);
        AFrag af; af.u[0]=u0; af.u[1]=u1; af.u[2]=u2; af.u[3]=u3;
        const int koff = ks * 32 + hi * 16;
        bf16x8 v0 = *(const bf16x8*)((const char*)Vts[b] + lc * 128 + (koff ^ S0));
        bf16x8 v1 = *(const bf16x8*)((const char*)Vts[b] + (lc + 32) * 128 + (koff ^ S1));
        mfma32(o0, af.v, v0);
        mfma32(o1, af.v, v1);
      }
      rs += __shfl_xor(rs, 32);
      ls += rs;
    }

    // ---- epilogue ----
    if (slot < 0) {
      const float inv = 1.0f / ls;
      float* Ob = O + (size_t)(head * SEQ + qw) * DH;
#pragma unroll
      for (int r = 0; r < 16; ++r) {
        const int row = (r & 3) + 8 * (r >> 2) + 4 * hi;
        const float iq = __shfl(inv, row);
        Ob[(size_t)row * DH + lc]      = o0[r] * iq;
        Ob[(size_t)row * DH + 32 + lc] = o1[r] * iq;
      }
    } else {
      bf16* po = wsO + (size_t)slot * (128 * 64);
#pragma unroll
      for (int r = 0; r < 16; ++r) {
        const int row = w * WQ + (r & 3) + 8 * (r >> 2) + 4 * hi;
        po[row * 64 + lc]      = (bf16)o0[r];
        po[row * 64 + 32 + lc] = (bf16)o1[r];
      }
      if (hi == 0) {
        wsM[slot * 128 + w * WQ + lc] = m;
        wsL[slot * 128 + w * WQ + lc] = ls;
      }
    }
  }
}

// merge nc partials per split q-block (exact online-softmax merge)
__global__ __launch_bounds__(256)
void fa_combine(float* __restrict__ O, const void* __restrict__ ws,
                const int Lt, const int nslot) {
  const bf16*  wsO = (const bf16*)((const char*)ws + 256);
  const float* wsM = (const float*)((const char*)ws + 256 + (size_t)nslot * 16384);
  const float* wsL = wsM + (size_t)nslot * 128;

  const int li = blockIdx.x * 256 + threadIdx.x;   // [0, 1024)
  const int dp = li & 7;
  const int r  = li >> 3;                          // [0, 128)
  const int sj = blockIdx.y;                       // split-j ordinal (desc)
  const int h  = blockIdx.z;

  // map sj -> (j, sbase, nc), same descending order as fa_fwd
  int j = 0, sbase = 0, nc = 0;
  {
    int cnt = 0;
    for (int jj = NJ - 1; jj >= 0; --jj) {
      const int ncj = (2 * jj + 2 + Lt - 1) / Lt;
      if (ncj > 1) {
        if (cnt == sj) { j = jj; nc = ncj; break; }
        ++cnt; sbase += ncj;
      }
    }
  }

  float M = -INFINITY;
  for (int c = 0; c < nc; ++c)
    M = fmaxf(M, wsM[((sbase + c) * NH + h) * 128 + r]);

  float lt = 0.f, o[8] = {0.f,0.f,0.f,0.f,0.f,0.f,0.f,0.f};
  for (int c = 0; c < nc; ++c) {
    const int slot = (sbase + c) * NH + h;
    const float wgt = exp2f(wsM[slot * 128 + r] - M);
    lt += wgt * wsL[slot * 128 + r];
    const bf16x8 a = *(const bf16x8*)(wsO + (size_t)slot * 8192 + r * 64 + dp * 8);
#pragma unroll
    for (int jj = 0; jj < 8; ++jj) o[jj] += wgt * (float)a[jj];
  }
  const float inv = 1.0f / lt;

  float* out = O + ((size_t)h * SEQ + j * QB + r) * DH + dp * 8;
#pragma unroll
  for (int jj = 0; jj < 8; ++jj) out[jj] = o[jj] * inv;
}

extern "C" void kernel_launch(void* const* d_in, const int* in_sizes, int n_in,
                              void* d_out, int out_size, void* d_ws, size_t ws_size,
                              hipStream_t stream) {
  const float* q = (const float*)d_in[0];
  const float* k = (const float*)d_in[1];
  const float* v = (const float*)d_in[2];
  float* out = (float*)d_out;

  // pick finest chunk length that fits ws; 64 = monolithic (max item = 64)
  const int cand[4] = {16, 22, 32, 64};
  int Lt = 64, nslot = 0, nitems = 0, nsj = 0;
  for (int ic = 0; ic < 4; ++ic) {
    const int L = cand[ic];
    int sl = 0, it = 0, js = 0;
    for (int j = 0; j < NJ; ++j) {
      const int nc = (2 * j + 2 + L - 1) / L;
      it += nc * NH;
      if (nc > 1) { sl += nc * NH; ++js; }
    }
    const size_t need = 256 + (size_t)sl * (16384 + 512 + 512);
    if (need <= ws_size || L == 64) { Lt = L; nslot = sl; nitems = it; nsj = js; break; }
  }

  zero_ctr<<<1, 64, 0, stream>>>((unsigned*)d_ws);
  fa_fwd<<<1024, 256, 0, stream>>>(q, k, v, out, d_ws, nitems, Lt, nslot);
  if (nsj > 0) fa_combine<<<dim3(4, nsj, NH), 256, 0, stream>>>(out, d_ws, Lt, nslot);
}